// Round 9
// baseline (600.613 us; speedup 1.0000x reference)
//
#include <hip/hip_runtime.h>
#include <hip/hip_bf16.h>

// Harness-provided kernel symbol kept (not required to do work).
__global__ void GraphEncoder_20555713479231_kernel() {}

__device__ __forceinline__ float bf2f_lo(unsigned u) { return __uint_as_float(u << 16); }
__device__ __forceinline__ float bf2f_hi(unsigned u) { return __uint_as_float(u & 0xffff0000u); }
__device__ __forceinline__ unsigned short f2bf(float f) {
  unsigned u = __float_as_uint(f);
  return (unsigned short)((u + 0x7fffu + ((u >> 16) & 1u)) >> 16);
}
__device__ __forceinline__ unsigned packbf(float a, float b) {
  return (unsigned)f2bf(a) | ((unsigned)f2bf(b) << 16);
}

// ---------------- CSR build ----------------
__global__ __launch_bounds__(256) void k_zero(int* __restrict__ p, int n) {
  int i = blockIdx.x * blockDim.x + threadIdx.x;
  if (i < n) p[i] = 0;
}

// histogram: per-dst degree AND per-dst neighbor-type counts (fused)
__global__ __launch_bounds__(256) void k_hist(const int* __restrict__ src,
                                              const int* __restrict__ dst,
                                              const int* __restrict__ types,
                                              int* __restrict__ deg,
                                              int* __restrict__ tcnt, int e) {
  int i = blockIdx.x * blockDim.x + threadIdx.x;
  if (i < e) {
    int d = dst[i];
    int ty = types[src[i]];
    atomicAdd(&deg[d], 1);
    atomicAdd(&tcnt[d * 3 + ty], 1);
  }
}

// parallel scan pass 1: per-block exclusive scan of (deg[i]+1); block totals to bsum
__global__ __launch_bounds__(256) void k_scan1(const int* __restrict__ deg,
                                               int* __restrict__ off,
                                               int* __restrict__ bsum, int n) {
  __shared__ int wsum[4];
  int tid = threadIdx.x;
  int gid = blockIdx.x * 256 + tid;
  int lane = tid & 63, wid = tid >> 6;
  int v = (gid < n) ? (deg[gid] + 1) : 0;
  int x = v;
  #pragma unroll
  for (int d = 1; d < 64; d <<= 1) {
    int t = __shfl_up(x, d);
    if (lane >= d) x += t;
  }
  if (lane == 63) wsum[wid] = x;
  __syncthreads();
  int wpre = 0;
  for (int k = 0; k < wid; ++k) wpre += wsum[k];
  if (gid < n) off[gid] = wpre + x - v;
  if (tid == 0) {
    int t = 0;
    #pragma unroll
    for (int k = 0; k < 4; ++k) t += wsum[k];
    bsum[blockIdx.x] = t;
  }
}

// pass 2: single block scans block sums (nb <= 256) exclusive; total -> off[n]
__global__ __launch_bounds__(256) void k_scan2(int* __restrict__ bsum,
                                               int* __restrict__ off, int nb, int n) {
  __shared__ int wsum[4];
  int tid = threadIdx.x;
  int lane = tid & 63, wid = tid >> 6;
  int v = (tid < nb) ? bsum[tid] : 0;
  int x = v;
  #pragma unroll
  for (int d = 1; d < 64; d <<= 1) {
    int t = __shfl_up(x, d);
    if (lane >= d) x += t;
  }
  if (lane == 63) wsum[wid] = x;
  __syncthreads();
  int wpre = 0;
  for (int k = 0; k < wid; ++k) wpre += wsum[k];
  if (tid < nb) bsum[tid] = wpre + x - v;
  if (tid == 0) {
    int t = 0;
    #pragma unroll
    for (int k = 0; k < 4; ++k) t += wsum[k];
    off[n] = t;
  }
}

// pass 3: add block prefix
__global__ __launch_bounds__(256) void k_scan3(int* __restrict__ off,
                                               const int* __restrict__ bsum, int n) {
  int gid = blockIdx.x * 256 + threadIdx.x;
  if (gid < n) off[gid] += bsum[blockIdx.x];
}

__global__ __launch_bounds__(256) void k_initpos(const int* __restrict__ off,
                                                 int* __restrict__ pos,
                                                 int* __restrict__ csr, int n) {
  int i = blockIdx.x * blockDim.x + threadIdx.x;
  if (i < n) {
    int o = off[i];
    csr[o] = i;  // self-loop occupies first slot
    pos[i] = o + 1;
  }
}

__global__ __launch_bounds__(256) void k_fill(const int* __restrict__ src,
                                              const int* __restrict__ dst,
                                              int* __restrict__ pos,
                                              int* __restrict__ csr, int e) {
  int i = blockIdx.x * blockDim.x + threadIdx.x;
  if (i < e) {
    int d = dst[i];
    int p = atomicAdd(&pos[d], 1);
    csr[p] = src[i];
  }
}

// ---------------- layer 0: emb @ W (3x16 @ 16x128) tables ----------------
// tlb: packed bf16 pairs (3 x 64 uints); trf: f32 (3 x 128)
__global__ __launch_bounds__(256) void k_embw(const float* __restrict__ emb,
                                              const float* __restrict__ wl,
                                              const float* __restrict__ wr,
                                              unsigned* __restrict__ tlb,
                                              float* __restrict__ trf) {
  int tid = threadIdx.x;
  if (tid >= 192) return;
  int row = tid >> 6, cp = tid & 63, c0 = cp * 2;
  float al0 = 0.f, al1 = 0.f, ar0 = 0.f, ar1 = 0.f;
  #pragma unroll
  for (int k = 0; k < 16; ++k) {
    float ev = emb[row * 16 + k];
    al0 += ev * wl[k * 128 + c0];
    al1 += ev * wl[k * 128 + c0 + 1];
    ar0 += ev * wr[k * 128 + c0];
    ar1 += ev * wr[k * 128 + c0 + 1];
  }
  tlb[row * 64 + cp] = packbf(al0, al1);
  *(float2*)(trf + row * 128 + c0) = make_float2(ar0, ar1);
}

// ---------------- layer-0 aggregation from precomputed type counts ----------------
// softmax over neighbors collapses to O = sum_ty n_ty * exp(c_ty) * xl_ty.
// One wave per node; counts read from tcnt (built during CSR histogram).
__global__ __launch_bounds__(256)
void k_agg0(const int* __restrict__ tcnt, const int* __restrict__ types,
            const unsigned* __restrict__ tlb, const float* __restrict__ trf,
            const float* __restrict__ att, const float* __restrict__ bias,
            const float* __restrict__ lng, const float* __restrict__ lnb,
            float* __restrict__ yout, int n) {
  int v = (blockIdx.x * blockDim.x + threadIdx.x) >> 6;
  int lane = threadIdx.x & 63;
  if (v >= n) return;
  v = __builtin_amdgcn_readfirstlane(v);
  int tyv = types[v];
  float cnt[3];
  cnt[0] = (float)tcnt[v * 3 + 0];
  cnt[1] = (float)tcnt[v * 3 + 1];
  cnt[2] = (float)tcnt[v * 3 + 2];
  cnt[tyv] += 1.f;  // self-loop
  int f0 = lane * 2;
  float2 xrv = *(const float2*)(trf + tyv * 128 + f0);
  float a0 = att[f0], a1 = att[f0 + 1];
  float s = 0.f, O0 = 0.f, O1 = 0.f;
  #pragma unroll
  for (int ty = 0; ty < 3; ++ty) {
    unsigned p = tlb[ty * 64 + lane];
    float x0 = bf2f_lo(p), x1 = bf2f_hi(p);
    float t0 = x0 + xrv.x; t0 = t0 > 0.f ? t0 : 0.2f * t0;
    float t1 = x1 + xrv.y; t1 = t1 > 0.f ? t1 : 0.2f * t1;
    float c = t0 * a0 + t1 * a1;
    c += __shfl_xor(c, 1);
    c += __shfl_xor(c, 2);
    c += __shfl_xor(c, 4);
    c += __shfl_xor(c, 8);
    float w = cnt[ty] * __expf(c);
    s += w;
    O0 = fmaf(w, x0, O0);
    O1 = fmaf(w, x1, O1);
  }
  float inv = 1.f / s;
  float o0 = O0 * inv + bias[f0];
  float o1 = O1 * inv + bias[f0 + 1];
  float sum = o0 + o1, sq = o0 * o0 + o1 * o1;
  #pragma unroll
  for (int d2 = 1; d2 < 64; d2 <<= 1) {
    sum += __shfl_xor(sum, d2);
    sq += __shfl_xor(sq, d2);
  }
  float mu = sum * (1.f / 128.f);
  float var = sq * (1.f / 128.f) - mu * mu;
  float rstd = rsqrtf(var + 1e-5f);
  float y0 = fmaxf((o0 - mu) * rstd * lng[f0] + lnb[f0], 0.f);
  float y1 = fmaxf((o1 - mu) * rstd * lng[f0 + 1] + lnb[f0 + 1], 0.f);
  *(float2*)(yout + (size_t)v * 128 + f0) = make_float2(y0, y1);
}

// ---------------- GEMM (VALU, LDS-tiled): x(Nx128) @ [Wl|Wr](128x256) ----------
// xl out: packed bf16 pairs (row = 64 uints); xr out: f32 (row = 128 floats)
__global__ __launch_bounds__(256)
void k_gemm(const float* __restrict__ x,
            const float* __restrict__ wl,
            const float* __restrict__ wr,
            unsigned* __restrict__ xlo, float* __restrict__ xro, int n) {
  __shared__ float xsh[32 * 128];  // [row][k]   16 KB
  __shared__ float wsh[32 * 256];  // [kk][col]  32 KB  (col<128 Wl, col>=128 Wr)
  int tid = threadIdx.x;
  int r0 = blockIdx.x * 32;
  #pragma unroll
  for (int i = 0; i < 4; ++i) {
    int j = i * 256 + tid;  // float4 idx: row = j>>5, kq = j&31
    int rr = r0 + (j >> 5);
    float4 v = make_float4(0.f, 0.f, 0.f, 0.f);
    if (rr < n) v = *(const float4*)(x + (size_t)rr * 128 + (j & 31) * 4);
    *(float4*)(xsh + (j >> 5) * 128 + (j & 31) * 4) = v;
  }
  int rg = tid >> 5;
  int cq = tid & 31;
  int cL = cq * 4;
  float acc[4][8];  // [row][0..3 = Wl cols cL.., 4..7 = Wr cols cL..]
  #pragma unroll
  for (int a = 0; a < 4; ++a)
    #pragma unroll
    for (int b = 0; b < 8; ++b) acc[a][b] = 0.f;
  for (int kc = 0; kc < 4; ++kc) {
    __syncthreads();
    #pragma unroll
    for (int i = 0; i < 8; ++i) {
      int j = i * 256 + tid;  // float4 idx: kk = j>>6, c = (j&63)*4
      int kk = j >> 6;
      int c = (j & 63) * 4;
      int k = kc * 32 + kk;
      float4 v = (c < 128) ? *(const float4*)(wl + (size_t)k * 128 + c)
                           : *(const float4*)(wr + (size_t)k * 128 + (c - 128));
      *(float4*)(wsh + kk * 256 + c) = v;
    }
    __syncthreads();
    #pragma unroll 4
    for (int kk = 0; kk < 32; ++kk) {
      float xv[4];
      #pragma unroll
      for (int a = 0; a < 4; ++a) xv[a] = xsh[(rg * 4 + a) * 128 + kc * 32 + kk];
      float4 w0 = *(float4*)(wsh + kk * 256 + cL);
      float4 w1 = *(float4*)(wsh + kk * 256 + 128 + cL);
      #pragma unroll
      for (int a = 0; a < 4; ++a) {
        acc[a][0] += xv[a] * w0.x; acc[a][1] += xv[a] * w0.y;
        acc[a][2] += xv[a] * w0.z; acc[a][3] += xv[a] * w0.w;
        acc[a][4] += xv[a] * w1.x; acc[a][5] += xv[a] * w1.y;
        acc[a][6] += xv[a] * w1.z; acc[a][7] += xv[a] * w1.w;
      }
    }
  }
  #pragma unroll
  for (int a = 0; a < 4; ++a) {
    int rr = r0 + rg * 4 + a;
    if (rr < n) {
      uint2 pk;
      pk.x = packbf(acc[a][0], acc[a][1]);
      pk.y = packbf(acc[a][2], acc[a][3]);
      *(uint2*)(xlo + (size_t)rr * 64 + (cL >> 1)) = pk;
      *(float4*)(xro + (size_t)rr * 128 + cL) =
          make_float4(acc[a][4], acc[a][5], acc[a][6], acc[a][7]);
    }
  }
}

// ---------------- fused aggregate + bias + residual + LN + ReLU ----------------
// one wave per dst node; lane owns features 2*lane, 2*lane+1; xl packed bf16.
// No-max softmax; unroll-4, 8 rows in flight; uniform (scalar) csr index loads.
__global__ __launch_bounds__(256)
void k_agg(const int* __restrict__ off, const int* __restrict__ csr,
           const unsigned* __restrict__ xl, const float* __restrict__ xr,
           const float* __restrict__ att, const float* __restrict__ bias,
           const float* __restrict__ xres,
           const float* __restrict__ lng, const float* __restrict__ lnb,
           float* __restrict__ yout, int n, int wide) {
  int v = (blockIdx.x * blockDim.x + threadIdx.x) >> 6;
  int lane = threadIdx.x & 63;
  if (v >= n) return;
  v = __builtin_amdgcn_readfirstlane(v);
  int f0 = lane * 2;
  float a0 = att[f0], a1 = att[f0 + 1];
  float2 rr2 = *(const float2*)(xr + (size_t)v * 128 + f0);
  int beg = off[v], end = off[v + 1];
  int last = end - 1;
  const unsigned* xlp = xl + lane;  // row r at xlp[r*64]
  unsigned p[4], q[4];
  #pragma unroll
  for (int j = 0; j < 4; ++j) p[j] = xlp[(size_t)csr[min(beg + j, last)] * 64];
  #pragma unroll
  for (int j = 0; j < 4; ++j) q[j] = xlp[(size_t)csr[min(beg + 4 + j, last)] * 64];
  float sa = 0.f, Oa0 = 0.f, Oa1 = 0.f;
  float sb = 0.f, Ob0 = 0.f, Ob1 = 0.f;
  for (int e = beg; e < end; e += 4) {
    unsigned np[4];
    #pragma unroll
    for (int j = 0; j < 4; ++j) np[j] = xlp[(size_t)csr[min(e + 8 + j, last)] * 64];
    float x0[4], x1[4], c[4];
    #pragma unroll
    for (int j = 0; j < 4; ++j) {
      x0[j] = bf2f_lo(p[j]);
      x1[j] = bf2f_hi(p[j]);
      float t0 = x0[j] + rr2.x; t0 = t0 > 0.f ? t0 : 0.2f * t0;
      float t1 = x1[j] + rr2.y; t1 = t1 > 0.f ? t1 : 0.2f * t1;
      c[j] = t0 * a0 + t1 * a1;
    }
    #pragma unroll
    for (int j = 0; j < 4; ++j) c[j] += __shfl_xor(c[j], 1);
    #pragma unroll
    for (int j = 0; j < 4; ++j) c[j] += __shfl_xor(c[j], 2);
    #pragma unroll
    for (int j = 0; j < 4; ++j) c[j] += __shfl_xor(c[j], 4);
    #pragma unroll
    for (int j = 0; j < 4; ++j) c[j] += __shfl_xor(c[j], 8);
    if (wide) {
      #pragma unroll
      for (int j = 0; j < 4; ++j) c[j] += __shfl_xor(c[j], 16);
      #pragma unroll
      for (int j = 0; j < 4; ++j) c[j] += __shfl_xor(c[j], 32);
    }
    float w[4];
    #pragma unroll
    for (int j = 0; j < 4; ++j) w[j] = (e + j < end) ? __expf(c[j]) : 0.f;
    sa += w[0]; Oa0 = fmaf(w[0], x0[0], Oa0); Oa1 = fmaf(w[0], x1[0], Oa1);
    sb += w[1]; Ob0 = fmaf(w[1], x0[1], Ob0); Ob1 = fmaf(w[1], x1[1], Ob1);
    sa += w[2]; Oa0 = fmaf(w[2], x0[2], Oa0); Oa1 = fmaf(w[2], x1[2], Oa1);
    sb += w[3]; Ob0 = fmaf(w[3], x0[3], Ob0); Ob1 = fmaf(w[3], x1[3], Ob1);
    #pragma unroll
    for (int j = 0; j < 4; ++j) { p[j] = q[j]; q[j] = np[j]; }
  }
  float s = sa + sb;
  float O0 = Oa0 + Ob0, O1 = Oa1 + Ob1;
  float inv = 1.f / s;
  float o0 = O0 * inv + bias[f0];
  float o1 = O1 * inv + bias[f0 + 1];
  if (xres) {
    float2 rs = *(const float2*)(xres + (size_t)v * 128 + f0);
    o0 += rs.x;
    o1 += rs.y;
  }
  float sum = o0 + o1, sq = o0 * o0 + o1 * o1;
  #pragma unroll
  for (int d2 = 1; d2 < 64; d2 <<= 1) {
    sum += __shfl_xor(sum, d2);
    sq += __shfl_xor(sq, d2);
  }
  float mu = sum * (1.f / 128.f);
  float var = sq * (1.f / 128.f) - mu * mu;
  float rstd = rsqrtf(var + 1e-5f);
  float y0 = fmaxf((o0 - mu) * rstd * lng[f0] + lnb[f0], 0.f);
  float y1 = fmaxf((o1 - mu) * rstd * lng[f0 + 1] + lnb[f0 + 1], 0.f);
  *(float2*)(yout + (size_t)v * 128 + f0) = make_float2(y0, y1);
}

// ---------------- launch ----------------
extern "C" void kernel_launch(void* const* d_in, const int* in_sizes, int n_in,
                              void* d_out, int out_size, void* d_ws, size_t ws_size,
                              hipStream_t stream) {
  (void)n_in; (void)out_size; (void)ws_size;
  const int* node_types = (const int*)d_in[0];
  const int* edge_index = (const int*)d_in[1];
  const float* emb = (const float*)d_in[2];
  const float* Wl0 = (const float*)d_in[3];
  const float* Wr0 = (const float*)d_in[4];
  const float* att0 = (const float*)d_in[5];
  const float* b0 = (const float*)d_in[6];
  const float* Wl1 = (const float*)d_in[7];
  const float* Wr1 = (const float*)d_in[8];
  const float* att1 = (const float*)d_in[9];
  const float* b1 = (const float*)d_in[10];
  const float* Wl2 = (const float*)d_in[11];
  const float* Wr2 = (const float*)d_in[12];
  const float* att2 = (const float*)d_in[13];
  const float* b2 = (const float*)d_in[14];
  const float* Wl3 = (const float*)d_in[15];
  const float* Wr3 = (const float*)d_in[16];
  const float* att3 = (const float*)d_in[17];
  const float* b3 = (const float*)d_in[18];
  const float* lng = (const float*)d_in[19];
  const float* lnb = (const float*)d_in[20];

  int n = in_sizes[0];
  int e = in_sizes[1] / 2;
  const int* srcp = edge_index;
  const int* dstp = edge_index + e;
  int nblocks = (n + 255) / 256;

  // workspace carve (256-byte aligned chunks); deg and tcnt adjacent so one
  // k_zero launch clears both.
  char* wsp = (char*)d_ws;
  size_t ofs = 0;
  int* deg = (int*)(wsp + ofs); ofs += (((size_t)n * 4) + 255) & ~(size_t)255;
  int* tcnt = (int*)(wsp + ofs); ofs += (((size_t)n * 12) + 255) & ~(size_t)255;
  int zlen = (int)(((char*)wsp + ofs - (char*)deg) / 4);
  int* off = (int*)(wsp + ofs); ofs += (((size_t)(n + 1) * 4) + 255) & ~(size_t)255;
  int* csr = (int*)(wsp + ofs); ofs += (((size_t)(e + n) * 4) + 255) & ~(size_t)255;
  int* bsum = (int*)(wsp + ofs); ofs += (((size_t)nblocks * 4) + 255) & ~(size_t)255;
  unsigned* xlb = (unsigned*)(wsp + ofs); ofs += (((size_t)n * 64 * 4) + 255) & ~(size_t)255;
  float* xrb = (float*)(wsp + ofs); ofs += (((size_t)n * 128 * 4) + 255) & ~(size_t)255;
  unsigned* tlb = (unsigned*)(wsp + ofs); ofs += 1024;
  float* trf = (float*)(wsp + ofs); ofs += 2048;
  int* pos = deg;  // deg dead after scan; reuse as fill cursor
  // xcur aliased onto d_out (f32): layer-0 k_agg0 writes every element before
  // any later read; final layer overwrites all of d_out.
  float* xcur = (float*)d_out;

  // CSR build + fused neighbor-type histogram (graph identical across layers)
  k_zero<<<(zlen + 255) / 256, 256, 0, stream>>>(deg, zlen);
  k_hist<<<(e + 255) / 256, 256, 0, stream>>>(srcp, dstp, node_types, deg, tcnt, e);
  k_scan1<<<nblocks, 256, 0, stream>>>(deg, off, bsum, n);
  k_scan2<<<1, 256, 0, stream>>>(bsum, off, nblocks, n);
  k_scan3<<<nblocks, 256, 0, stream>>>(off, bsum, n);
  k_initpos<<<nblocks, 256, 0, stream>>>(off, pos, csr, n);
  k_fill<<<(e + 255) / 256, 256, 0, stream>>>(srcp, dstp, pos, csr, e);

  int aggBlocks = (n * 64 + 255) / 256;

  // layer 0: type-table aggregation from precomputed counts
  k_embw<<<1, 256, 0, stream>>>(emb, Wl0, Wr0, tlb, trf);
  k_agg0<<<aggBlocks, 256, 0, stream>>>(tcnt, node_types, tlb, trf,
                                        att0, b0, lng, lnb, xcur, n);

  int gemmBlocks = (n + 31) / 32;

  // layer 1
  k_gemm<<<gemmBlocks, 256, 0, stream>>>(xcur, Wl1, Wr1, xlb, xrb, n);
  k_agg<<<aggBlocks, 256, 0, stream>>>(off, csr, xlb, xrb, att1, b1, xcur,
                                       lng + 128, lnb + 128, xcur, n, 0);
  // layer 2
  k_gemm<<<gemmBlocks, 256, 0, stream>>>(xcur, Wl2, Wr2, xlb, xrb, n);
  k_agg<<<aggBlocks, 256, 0, stream>>>(off, csr, xlb, xrb, att2, b2, xcur,
                                       lng + 256, lnb + 256, xcur, n, 0);
  // layer 3 (single head, wide reduce)
  k_gemm<<<gemmBlocks, 256, 0, stream>>>(xcur, Wl3, Wr3, xlb, xrb, n);
  k_agg<<<aggBlocks, 256, 0, stream>>>(off, csr, xlb, xrb, att3, b3, xcur,
                                       lng + 384, lnb + 384, (float*)d_out, n, 1);
}

// Round 10
// 550.333 us; speedup vs baseline: 1.0914x; 1.0914x over previous
//
#include <hip/hip_runtime.h>
#include <hip/hip_bf16.h>

// Harness-provided kernel symbol kept (not required to do work).
__global__ void GraphEncoder_20555713479231_kernel() {}

__device__ __forceinline__ float bf2f_lo(unsigned u) { return __uint_as_float(u << 16); }
__device__ __forceinline__ float bf2f_hi(unsigned u) { return __uint_as_float(u & 0xffff0000u); }
__device__ __forceinline__ unsigned short f2bf(float f) {
  unsigned u = __float_as_uint(f);
  return (unsigned short)((u + 0x7fffu + ((u >> 16) & 1u)) >> 16);
}
__device__ __forceinline__ unsigned packbf(float a, float b) {
  return (unsigned)f2bf(a) | ((unsigned)f2bf(b) << 16);
}

// ---------------- CSR build ----------------
__global__ __launch_bounds__(256) void k_zero(int* __restrict__ p, int n) {
  int i = blockIdx.x * blockDim.x + threadIdx.x;
  if (i < n) p[i] = 0;
}

__global__ __launch_bounds__(256) void k_hist(const int* __restrict__ dst,
                                              int* __restrict__ deg, int e) {
  int i = blockIdx.x * blockDim.x + threadIdx.x;
  if (i < e) atomicAdd(&deg[dst[i]], 1);
}

// parallel scan pass 1: per-block exclusive scan of (deg[i]+1); block totals to bsum
__global__ __launch_bounds__(256) void k_scan1(const int* __restrict__ deg,
                                               int* __restrict__ off,
                                               int* __restrict__ bsum, int n) {
  __shared__ int wsum[4];
  int tid = threadIdx.x;
  int gid = blockIdx.x * 256 + tid;
  int lane = tid & 63, wid = tid >> 6;
  int v = (gid < n) ? (deg[gid] + 1) : 0;
  int x = v;
  #pragma unroll
  for (int d = 1; d < 64; d <<= 1) {
    int t = __shfl_up(x, d);
    if (lane >= d) x += t;
  }
  if (lane == 63) wsum[wid] = x;
  __syncthreads();
  int wpre = 0;
  for (int k = 0; k < wid; ++k) wpre += wsum[k];
  if (gid < n) off[gid] = wpre + x - v;
  if (tid == 0) {
    int t = 0;
    #pragma unroll
    for (int k = 0; k < 4; ++k) t += wsum[k];
    bsum[blockIdx.x] = t;
  }
}

// pass 2: single block scans block sums (nb <= 256) exclusive; total -> off[n]
__global__ __launch_bounds__(256) void k_scan2(int* __restrict__ bsum,
                                               int* __restrict__ off, int nb, int n) {
  __shared__ int wsum[4];
  int tid = threadIdx.x;
  int lane = tid & 63, wid = tid >> 6;
  int v = (tid < nb) ? bsum[tid] : 0;
  int x = v;
  #pragma unroll
  for (int d = 1; d < 64; d <<= 1) {
    int t = __shfl_up(x, d);
    if (lane >= d) x += t;
  }
  if (lane == 63) wsum[wid] = x;
  __syncthreads();
  int wpre = 0;
  for (int k = 0; k < wid; ++k) wpre += wsum[k];
  if (tid < nb) bsum[tid] = wpre + x - v;
  if (tid == 0) {
    int t = 0;
    #pragma unroll
    for (int k = 0; k < 4; ++k) t += wsum[k];
    off[n] = t;
  }
}

// pass 3: add block prefix
__global__ __launch_bounds__(256) void k_scan3(int* __restrict__ off,
                                               const int* __restrict__ bsum, int n) {
  int gid = blockIdx.x * 256 + threadIdx.x;
  if (gid < n) off[gid] += bsum[blockIdx.x];
}

__global__ __launch_bounds__(256) void k_initpos(const int* __restrict__ off,
                                                 int* __restrict__ pos,
                                                 int* __restrict__ csr, int n) {
  int i = blockIdx.x * blockDim.x + threadIdx.x;
  if (i < n) {
    int o = off[i];
    csr[o] = i;  // self-loop occupies first slot
    pos[i] = o + 1;
  }
}

__global__ __launch_bounds__(256) void k_fill(const int* __restrict__ src,
                                              const int* __restrict__ dst,
                                              int* __restrict__ pos,
                                              int* __restrict__ csr, int e) {
  int i = blockIdx.x * blockDim.x + threadIdx.x;
  if (i < e) {
    int d = dst[i];
    int p = atomicAdd(&pos[d], 1);
    csr[p] = src[i];
  }
}

// ---------------- layer 0: emb @ W (3x16 @ 16x128) tables ----------------
// tlb: packed bf16 pairs (3 x 64 uints); trf: f32 (3 x 128)
__global__ __launch_bounds__(256) void k_embw(const float* __restrict__ emb,
                                              const float* __restrict__ wl,
                                              const float* __restrict__ wr,
                                              unsigned* __restrict__ tlb,
                                              float* __restrict__ trf) {
  int tid = threadIdx.x;
  if (tid >= 192) return;
  int row = tid >> 6, cp = tid & 63, c0 = cp * 2;
  float al0 = 0.f, al1 = 0.f, ar0 = 0.f, ar1 = 0.f;
  #pragma unroll
  for (int k = 0; k < 16; ++k) {
    float ev = emb[row * 16 + k];
    al0 += ev * wl[k * 128 + c0];
    al1 += ev * wl[k * 128 + c0 + 1];
    ar0 += ev * wr[k * 128 + c0];
    ar1 += ev * wr[k * 128 + c0 + 1];
  }
  tlb[row * 64 + cp] = packbf(al0, al1);
  *(float2*)(trf + row * 128 + c0) = make_float2(ar0, ar1);
}

// ---------------- layer-0 aggregation via neighbor-type histogram ----------------
// xl[src] takes only 3 values -> softmax collapses to O = sum_ty n_ty*exp(c_ty)*xl_ty.
// One wave per node; output written as packed bf16 (pipeline activation format).
__global__ __launch_bounds__(256)
void k_agg0(const int* __restrict__ off, const int* __restrict__ csr,
            const int* __restrict__ types,
            const unsigned* __restrict__ tlb, const float* __restrict__ trf,
            const float* __restrict__ att, const float* __restrict__ bias,
            const float* __restrict__ lng, const float* __restrict__ lnb,
            unsigned* __restrict__ yout, int n) {
  int v = (blockIdx.x * blockDim.x + threadIdx.x) >> 6;
  int lane = threadIdx.x & 63;
  if (v >= n) return;
  v = __builtin_amdgcn_readfirstlane(v);
  int beg = off[v], end = off[v + 1];
  // phase 1: edge-parallel type histogram (ballot/popcount)
  int c0 = 0, c1 = 0, c2 = 0;
  for (int base = beg; base < end; base += 64) {
    int e = base + lane;
    bool act = e < end;
    int u = act ? csr[e] : 0;
    int ty = act ? types[u] : 3;
    c0 += __popcll(__ballot(ty == 0));
    c1 += __popcll(__ballot(ty == 1));
    c2 += __popcll(__ballot(ty == 2));
  }
  float cnt[3] = {(float)c0, (float)c1, (float)c2};
  // phase 2: feature-parallel, 3 candidate logits per head
  int f0 = lane * 2;
  int tyv = types[v];
  float2 xrv = *(const float2*)(trf + tyv * 128 + f0);
  float a0 = att[f0], a1 = att[f0 + 1];
  float s = 0.f, O0 = 0.f, O1 = 0.f;
  #pragma unroll
  for (int ty = 0; ty < 3; ++ty) {
    unsigned p = tlb[ty * 64 + lane];
    float x0 = bf2f_lo(p), x1 = bf2f_hi(p);
    float t0 = x0 + xrv.x; t0 = t0 > 0.f ? t0 : 0.2f * t0;
    float t1 = x1 + xrv.y; t1 = t1 > 0.f ? t1 : 0.2f * t1;
    float c = t0 * a0 + t1 * a1;
    c += __shfl_xor(c, 1);
    c += __shfl_xor(c, 2);
    c += __shfl_xor(c, 4);
    c += __shfl_xor(c, 8);
    float w = cnt[ty] * __expf(c);
    s += w;
    O0 = fmaf(w, x0, O0);
    O1 = fmaf(w, x1, O1);
  }
  float inv = 1.f / s;
  float o0 = O0 * inv + bias[f0];
  float o1 = O1 * inv + bias[f0 + 1];
  float sum = o0 + o1, sq = o0 * o0 + o1 * o1;
  #pragma unroll
  for (int d2 = 1; d2 < 64; d2 <<= 1) {
    sum += __shfl_xor(sum, d2);
    sq += __shfl_xor(sq, d2);
  }
  float mu = sum * (1.f / 128.f);
  float var = sq * (1.f / 128.f) - mu * mu;
  float rstd = rsqrtf(var + 1e-5f);
  float y0 = fmaxf((o0 - mu) * rstd * lng[f0] + lnb[f0], 0.f);
  float y1 = fmaxf((o1 - mu) * rstd * lng[f0 + 1] + lnb[f0 + 1], 0.f);
  yout[(size_t)v * 64 + lane] = packbf(y0, y1);
}

// ---------------- GEMM (VALU, LDS-tiled): x(Nx128 bf16) @ [Wl|Wr](128x256) ----------
// x in: packed bf16 pairs (row = 64 uints); xl/xr out: packed bf16 (row = 64 uints each)
__global__ __launch_bounds__(256)
void k_gemm(const unsigned* __restrict__ x,
            const float* __restrict__ wl,
            const float* __restrict__ wr,
            unsigned* __restrict__ xlo, unsigned* __restrict__ xro, int n) {
  __shared__ float xsh[32 * 128];  // [row][k]   16 KB (unpacked to f32 at staging)
  __shared__ float wsh[32 * 256];  // [kk][col]  32 KB  (col<128 Wl, col>=128 Wr)
  int tid = threadIdx.x;
  int r0 = blockIdx.x * 32;
  #pragma unroll
  for (int i = 0; i < 8; ++i) {
    int j = i * 256 + tid;  // uint idx 0..2047: row = j>>6, kp = j&63
    int rr = r0 + (j >> 6);
    unsigned p = 0;
    if (rr < n) p = x[(size_t)rr * 64 + (j & 63)];
    *(float2*)(xsh + (j >> 6) * 128 + (j & 63) * 2) = make_float2(bf2f_lo(p), bf2f_hi(p));
  }
  int rg = tid >> 5;
  int cq = tid & 31;
  int cL = cq * 4;
  float acc[4][8];  // [row][0..3 = Wl cols cL.., 4..7 = Wr cols cL..]
  #pragma unroll
  for (int a = 0; a < 4; ++a)
    #pragma unroll
    for (int b = 0; b < 8; ++b) acc[a][b] = 0.f;
  for (int kc = 0; kc < 4; ++kc) {
    __syncthreads();
    #pragma unroll
    for (int i = 0; i < 8; ++i) {
      int j = i * 256 + tid;  // float4 idx: kk = j>>6, c = (j&63)*4
      int kk = j >> 6;
      int c = (j & 63) * 4;
      int k = kc * 32 + kk;
      float4 v = (c < 128) ? *(const float4*)(wl + (size_t)k * 128 + c)
                           : *(const float4*)(wr + (size_t)k * 128 + (c - 128));
      *(float4*)(wsh + kk * 256 + c) = v;
    }
    __syncthreads();
    #pragma unroll 4
    for (int kk = 0; kk < 32; ++kk) {
      float xv[4];
      #pragma unroll
      for (int a = 0; a < 4; ++a) xv[a] = xsh[(rg * 4 + a) * 128 + kc * 32 + kk];
      float4 w0 = *(float4*)(wsh + kk * 256 + cL);
      float4 w1 = *(float4*)(wsh + kk * 256 + 128 + cL);
      #pragma unroll
      for (int a = 0; a < 4; ++a) {
        acc[a][0] += xv[a] * w0.x; acc[a][1] += xv[a] * w0.y;
        acc[a][2] += xv[a] * w0.z; acc[a][3] += xv[a] * w0.w;
        acc[a][4] += xv[a] * w1.x; acc[a][5] += xv[a] * w1.y;
        acc[a][6] += xv[a] * w1.z; acc[a][7] += xv[a] * w1.w;
      }
    }
  }
  #pragma unroll
  for (int a = 0; a < 4; ++a) {
    int rr = r0 + rg * 4 + a;
    if (rr < n) {
      uint2 pk, pr;
      pk.x = packbf(acc[a][0], acc[a][1]);
      pk.y = packbf(acc[a][2], acc[a][3]);
      pr.x = packbf(acc[a][4], acc[a][5]);
      pr.y = packbf(acc[a][6], acc[a][7]);
      *(uint2*)(xlo + (size_t)rr * 64 + (cL >> 1)) = pk;
      *(uint2*)(xro + (size_t)rr * 64 + (cL >> 1)) = pr;
    }
  }
}

// ---------------- fused aggregate + bias + residual + LN + ReLU ----------------
// one wave per dst node; lane owns features 2*lane, 2*lane+1; all activations
// packed bf16. No-max softmax; unroll-2, prefetch-4 (proven round-8 structure).
// Output: packed bf16 to ybf (if non-null) else f32 to yf32.
__global__ __launch_bounds__(256)
void k_agg(const int* __restrict__ off, const int* __restrict__ csr,
           const unsigned* __restrict__ xl, const unsigned* __restrict__ xr,
           const float* __restrict__ att, const float* __restrict__ bias,
           const unsigned* __restrict__ xres,
           const float* __restrict__ lng, const float* __restrict__ lnb,
           unsigned* __restrict__ ybf, float* __restrict__ yf32, int n, int wide) {
  int v = (blockIdx.x * blockDim.x + threadIdx.x) >> 6;
  int lane = threadIdx.x & 63;
  if (v >= n) return;
  v = __builtin_amdgcn_readfirstlane(v);
  int f0 = lane * 2;
  float a0 = att[f0], a1 = att[f0 + 1];
  unsigned rv = xr[(size_t)v * 64 + lane];
  float r0 = bf2f_lo(rv), r1 = bf2f_hi(rv);
  int beg = off[v], end = off[v + 1];
  int last = end - 1;
  const unsigned* xlp = xl + lane;  // row r at xlp[r*64]
  int iA = csr[beg];
  int iB = csr[min(beg + 1, last)];
  int iC = csr[min(beg + 2, last)];
  int iD = csr[min(beg + 3, last)];
  unsigned pA = xlp[(size_t)iA * 64];
  unsigned pB = xlp[(size_t)iB * 64];
  unsigned pC = xlp[(size_t)iC * 64];
  unsigned pD = xlp[(size_t)iD * 64];
  float sa = 0.f, Oa0 = 0.f, Oa1 = 0.f;
  float sb = 0.f, Ob0 = 0.f, Ob1 = 0.f;
  for (int e = beg; e < end; e += 2) {
    int i4 = csr[min(e + 4, last)];
    int i5 = csr[min(e + 5, last)];
    unsigned p4 = xlp[(size_t)i4 * 64];
    unsigned p5 = xlp[(size_t)i5 * 64];
    float x0a = bf2f_lo(pA), x1a = bf2f_hi(pA);
    float x0b = bf2f_lo(pB), x1b = bf2f_hi(pB);
    float t0a = x0a + r0; t0a = t0a > 0.f ? t0a : 0.2f * t0a;
    float t1a = x1a + r1; t1a = t1a > 0.f ? t1a : 0.2f * t1a;
    float t0b = x0b + r0; t0b = t0b > 0.f ? t0b : 0.2f * t0b;
    float t1b = x1b + r1; t1b = t1b > 0.f ? t1b : 0.2f * t1b;
    float ca = t0a * a0 + t1a * a1;
    float cb = t0b * a0 + t1b * a1;
    ca += __shfl_xor(ca, 1); cb += __shfl_xor(cb, 1);
    ca += __shfl_xor(ca, 2); cb += __shfl_xor(cb, 2);
    ca += __shfl_xor(ca, 4); cb += __shfl_xor(cb, 4);
    ca += __shfl_xor(ca, 8); cb += __shfl_xor(cb, 8);
    if (wide) {
      ca += __shfl_xor(ca, 16); cb += __shfl_xor(cb, 16);
      ca += __shfl_xor(ca, 32); cb += __shfl_xor(cb, 32);
    }
    float wa = __expf(ca);
    float wb = (e + 1 < end) ? __expf(cb) : 0.f;
    sa += wa; Oa0 = fmaf(wa, x0a, Oa0); Oa1 = fmaf(wa, x1a, Oa1);
    sb += wb; Ob0 = fmaf(wb, x0b, Ob0); Ob1 = fmaf(wb, x1b, Ob1);
    pA = pC; pB = pD; pC = p4; pD = p5;
  }
  float s = sa + sb;
  float O0 = Oa0 + Ob0, O1 = Oa1 + Ob1;
  float inv = 1.f / s;
  float o0 = O0 * inv + bias[f0];
  float o1 = O1 * inv + bias[f0 + 1];
  if (xres) {
    unsigned rs = xres[(size_t)v * 64 + lane];
    o0 += bf2f_lo(rs);
    o1 += bf2f_hi(rs);
  }
  float sum = o0 + o1, sq = o0 * o0 + o1 * o1;
  #pragma unroll
  for (int d2 = 1; d2 < 64; d2 <<= 1) {
    sum += __shfl_xor(sum, d2);
    sq += __shfl_xor(sq, d2);
  }
  float mu = sum * (1.f / 128.f);
  float var = sq * (1.f / 128.f) - mu * mu;
  float rstd = rsqrtf(var + 1e-5f);
  float y0 = fmaxf((o0 - mu) * rstd * lng[f0] + lnb[f0], 0.f);
  float y1 = fmaxf((o1 - mu) * rstd * lng[f0 + 1] + lnb[f0 + 1], 0.f);
  if (yf32) {
    *(float2*)(yf32 + (size_t)v * 128 + f0) = make_float2(y0, y1);
  } else {
    ybf[(size_t)v * 64 + lane] = packbf(y0, y1);
  }
}

// ---------------- launch ----------------
extern "C" void kernel_launch(void* const* d_in, const int* in_sizes, int n_in,
                              void* d_out, int out_size, void* d_ws, size_t ws_size,
                              hipStream_t stream) {
  (void)n_in; (void)out_size; (void)ws_size;
  const int* node_types = (const int*)d_in[0];
  const int* edge_index = (const int*)d_in[1];
  const float* emb = (const float*)d_in[2];
  const float* Wl0 = (const float*)d_in[3];
  const float* Wr0 = (const float*)d_in[4];
  const float* att0 = (const float*)d_in[5];
  const float* b0 = (const float*)d_in[6];
  const float* Wl1 = (const float*)d_in[7];
  const float* Wr1 = (const float*)d_in[8];
  const float* att1 = (const float*)d_in[9];
  const float* b1 = (const float*)d_in[10];
  const float* Wl2 = (const float*)d_in[11];
  const float* Wr2 = (const float*)d_in[12];
  const float* att2 = (const float*)d_in[13];
  const float* b2 = (const float*)d_in[14];
  const float* Wl3 = (const float*)d_in[15];
  const float* Wr3 = (const float*)d_in[16];
  const float* att3 = (const float*)d_in[17];
  const float* b3 = (const float*)d_in[18];
  const float* lng = (const float*)d_in[19];
  const float* lnb = (const float*)d_in[20];

  int n = in_sizes[0];
  int e = in_sizes[1] / 2;
  const int* srcp = edge_index;
  const int* dstp = edge_index + e;
  int nblocks = (n + 255) / 256;

  // workspace carve (256-byte aligned chunks)
  char* wsp = (char*)d_ws;
  size_t ofs = 0;
  int* deg = (int*)(wsp + ofs); ofs += (((size_t)n * 4) + 255) & ~(size_t)255;
  int* off = (int*)(wsp + ofs); ofs += (((size_t)(n + 1) * 4) + 255) & ~(size_t)255;
  int* csr = (int*)(wsp + ofs); ofs += (((size_t)(e + n) * 4) + 255) & ~(size_t)255;
  int* bsum = (int*)(wsp + ofs); ofs += (((size_t)nblocks * 4) + 255) & ~(size_t)255;
  unsigned* xlb = (unsigned*)(wsp + ofs); ofs += (((size_t)n * 64 * 4) + 255) & ~(size_t)255;
  unsigned* xrb = (unsigned*)(wsp + ofs); ofs += (((size_t)n * 64 * 4) + 255) & ~(size_t)255;
  unsigned* xcur = (unsigned*)(wsp + ofs); ofs += (((size_t)n * 64 * 4) + 255) & ~(size_t)255;
  unsigned* tlb = (unsigned*)(wsp + ofs); ofs += 1024;
  float* trf = (float*)(wsp + ofs); ofs += 2048;
  int* pos = deg;  // deg dead after scan; reuse as fill cursor

  // CSR build (graph identical across all 4 layers)
  k_zero<<<nblocks, 256, 0, stream>>>(deg, n);
  k_hist<<<(e + 255) / 256, 256, 0, stream>>>(dstp, deg, e);
  k_scan1<<<nblocks, 256, 0, stream>>>(deg, off, bsum, n);
  k_scan2<<<1, 256, 0, stream>>>(bsum, off, nblocks, n);
  k_scan3<<<nblocks, 256, 0, stream>>>(off, bsum, n);
  k_initpos<<<nblocks, 256, 0, stream>>>(off, pos, csr, n);
  k_fill<<<(e + 255) / 256, 256, 0, stream>>>(srcp, dstp, pos, csr, e);

  int aggBlocks = (n * 64 + 255) / 256;

  // layer 0: type-table aggregation (ballot histogram; writes bf16 xcur)
  k_embw<<<1, 256, 0, stream>>>(emb, Wl0, Wr0, tlb, trf);
  k_agg0<<<aggBlocks, 256, 0, stream>>>(off, csr, node_types, tlb, trf,
                                        att0, b0, lng, lnb, xcur, n);

  int gemmBlocks = (n + 31) / 32;

  // layer 1
  k_gemm<<<gemmBlocks, 256, 0, stream>>>(xcur, Wl1, Wr1, xlb, xrb, n);
  k_agg<<<aggBlocks, 256, 0, stream>>>(off, csr, xlb, xrb, att1, b1, xcur,
                                       lng + 128, lnb + 128, xcur, (float*)0, n, 0);
  // layer 2
  k_gemm<<<gemmBlocks, 256, 0, stream>>>(xcur, Wl2, Wr2, xlb, xrb, n);
  k_agg<<<aggBlocks, 256, 0, stream>>>(off, csr, xlb, xrb, att2, b2, xcur,
                                       lng + 256, lnb + 256, xcur, (float*)0, n, 0);
  // layer 3 (single head, wide reduce; f32 output to d_out)
  k_gemm<<<gemmBlocks, 256, 0, stream>>>(xcur, Wl3, Wr3, xlb, xrb, n);
  k_agg<<<aggBlocks, 256, 0, stream>>>(off, csr, xlb, xrb, att3, b3, xcur,
                                       lng + 384, lnb + 384, (unsigned*)0, (float*)d_out, n, 1);
}